// Round 9
// baseline (305.974 us; speedup 1.0000x reference)
//
#include <hip/hip_runtime.h>
#include <math.h>

#define NB 8192
#define T 65
#define Q 20
#define D 100
#define D4 25        // D/4
#define SP4 5        // sS row pitch in float4 (= Q floats exactly)

__global__ __launch_bounds__(256, 4) void attn_fused_kernel(
    const float* __restrict__ Hg,   // [B,T,D]
    const float* __restrict__ Ug,   // [B,Q,D]
    const float* __restrict__ Ws1,  // [T,D] (tiled single row)
    const float* __restrict__ Ws2,  // [Q,D]
    const float* __restrict__ Ws3,  // [T,D]
    float* __restrict__ Gg)         // [B,T,4D]
{
    // 26000 + 8400 + 5200 + 800 + 80 + 260 = 40740 B -> 4 blocks/CU (160 KiB)
    __shared__ float4 sH4[T*D4];          // 26000 B
    __shared__ float4 sU3e4[(Q+1)*D4];    //  8400 B: rows 0..19 = U*w3, row 20 = w1
    __shared__ float4 sS4[T*SP4];         //  5200 B (scores -> at in place)
    __shared__ float4 sHtilP[2][D4];      //   800 B (waves 0-1 partials)
    __shared__ float4 sU1q4[5];           //    80 B
    __shared__ float  sScal[T];           //   260 B: h1 -> beta -> bsm (in place)

    const int b    = blockIdx.x;
    const int tid  = threadIdx.x;
    const int wv   = tid >> 6;
    const int lane = tid & 63;
    const float4* Hb = (const float4*)(Hg + (size_t)b * (T*D));
    const float4* Ub = (const float4*)(Ug + (size_t)b * (Q*D));
    float* Gb = Gg + (size_t)b * (T*4*D);
    float* sSf = (float*)sS4;

    // ---- P1: stage H; build U*w3 from in-flight regs; w1 row ----
    for (int i = tid; i < T*D4; i += 256) sH4[i] = Hb[i];
    {
        const float4* w3g = (const float4*)Ws3;   // row 0 (all rows identical)
        for (int i = tid; i < Q*D4; i += 256) {
            const float4 u = Ub[i];
            const int dd = i - (i/D4)*D4;
            const float4 w = w3g[dd];
            float4 v; v.x=u.x*w.x; v.y=u.y*w.y; v.z=u.z*w.z; v.w=u.w*w.w;
            sU3e4[i] = v;
        }
        if (tid < D4) sU3e4[Q*D4 + tid] = ((const float4*)Ws1)[tid];
    }
    __syncthreads();   // bar1

    // ---- P3: S''[t,c] = H[t]·U3e[c] (65x21 GEMM; 3t x 3c, 154 lanes, waves 0-2)
    //      wave 3 (tid 192..211) concurrently: U1[q] = U[q]·w2 from GLOBAL (L2-warm)
    if (tid < 154) {
        const int tg = tid / 7;          // 0..21
        const int jg = tid - tg*7;       // 0..6
        int rb0 = ((tg*3 + 0) < T ? (tg*3 + 0) : T-1) * D4;
        int rb1 = ((tg*3 + 1) < T ? (tg*3 + 1) : T-1) * D4;
        int rb2 = ((tg*3 + 2) < T ? (tg*3 + 2) : T-1) * D4;
        float acc[3][3];
        #pragma unroll
        for (int i = 0; i < 3; ++i)
            #pragma unroll
            for (int k = 0; k < 3; ++k) acc[i][k] = 0.f;
        #pragma unroll 5
        for (int d4 = 0; d4 < D4; ++d4) {
            float4 h0 = sH4[rb0 + d4];
            float4 h1 = sH4[rb1 + d4];
            float4 h2 = sH4[rb2 + d4];
            #pragma unroll
            for (int k = 0; k < 3; ++k) {
                const float4 w = sU3e4[(jg*3+k)*D4 + d4];
                acc[0][k] = fmaf(h0.x, w.x, acc[0][k]); acc[0][k] = fmaf(h0.y, w.y, acc[0][k]);
                acc[0][k] = fmaf(h0.z, w.z, acc[0][k]); acc[0][k] = fmaf(h0.w, w.w, acc[0][k]);
                acc[1][k] = fmaf(h1.x, w.x, acc[1][k]); acc[1][k] = fmaf(h1.y, w.y, acc[1][k]);
                acc[1][k] = fmaf(h1.z, w.z, acc[1][k]); acc[1][k] = fmaf(h1.w, w.w, acc[1][k]);
                acc[2][k] = fmaf(h2.x, w.x, acc[2][k]); acc[2][k] = fmaf(h2.y, w.y, acc[2][k]);
                acc[2][k] = fmaf(h2.z, w.z, acc[2][k]); acc[2][k] = fmaf(h2.w, w.w, acc[2][k]);
            }
        }
        #pragma unroll
        for (int i = 0; i < 3; ++i) {
            const int t = tg*3 + i;
            if (t < T) {
                #pragma unroll
                for (int k = 0; k < 3; ++k) {
                    const int cc = jg*3 + k;
                    if (cc < Q) sSf[t*Q + cc] = acc[i][k];
                    else        sScal[t] = acc[i][k];     // cc == 20: h1[t]
                }
            }
        }
    } else if (tid >= 192 && tid < 192 + Q) {
        const int q = tid - 192;
        const float4* ur = Ub + q*D4;                     // global, L2-warm
        const float4* w2 = (const float4*)Ws2;
        float acc = 0.f;
        #pragma unroll 5
        for (int k = 0; k < D4; ++k) {
            const float4 u = ur[k], w = w2[k];
            acc = fmaf(u.x, w.x, acc); acc = fmaf(u.y, w.y, acc);
            acc = fmaf(u.z, w.z, acc); acc = fmaf(u.w, w.w, acc);
        }
        ((float*)sU1q4)[q] = acc;
    }
    __syncthreads();   // bar2

    // ---- P4: add U1, softmax over q (in place), beta[t] = h1[t] + max ----
    if (tid < T) {
        const int t = tid;
        float4 r[SP4];
        #pragma unroll
        for (int c = 0; c < SP4; ++c) {
            r[c] = sS4[t*SP4 + c];
            const float4 u1 = sU1q4[c];
            r[c].x += u1.x; r[c].y += u1.y; r[c].z += u1.z; r[c].w += u1.w;
        }
        float m = -1e30f;
        #pragma unroll
        for (int c = 0; c < SP4; ++c)
            m = fmaxf(m, fmaxf(fmaxf(r[c].x, r[c].y), fmaxf(r[c].z, r[c].w)));
        float s = 0.f;
        #pragma unroll
        for (int c = 0; c < SP4; ++c) {
            r[c].x = __expf(r[c].x - m); r[c].y = __expf(r[c].y - m);
            r[c].z = __expf(r[c].z - m); r[c].w = __expf(r[c].w - m);
            s += r[c].x + r[c].y + r[c].z + r[c].w;
        }
        const float inv = 1.f / s;
        #pragma unroll
        for (int c = 0; c < SP4; ++c) {
            r[c].x *= inv; r[c].y *= inv; r[c].z *= inv; r[c].w *= inv;
            sS4[t*SP4 + c] = r[c];
        }
        sScal[t] = sScal[t] + m;     // beta[t] = h1[t] + m (in place)
    }
    __syncthreads();   // bar3

    // ---- P5: softmax over t of beta (wave 0; lane 0 also owns t=64), in place ----
    if (tid < 64) {
        const float v0 = sScal[tid];
        const float v1 = (tid == 0) ? sScal[64] : -1e30f;
        float mx = fmaxf(v0, v1);
        #pragma unroll
        for (int off = 32; off >= 1; off >>= 1)
            mx = fmaxf(mx, __shfl_xor(mx, off, 64));
        const float e0 = __expf(v0 - mx);
        const float e1 = (tid == 0) ? __expf(v1 - mx) : 0.f;
        float s = e0 + e1;
        #pragma unroll
        for (int off = 32; off >= 1; off >>= 1)
            s += __shfl_xor(s, off, 64);
        const float inv = 1.f / s;
        sScal[tid] = e0 * inv;
        if (tid == 0) sScal[64] = e1 * inv;
    }
    __syncthreads();   // bar4

    // ---- P6: Htil partials on waves 0-1 (even/odd t), from sH4 ----
    if (wv < 2 && lane < D4) {
        float4 acc = {0.f, 0.f, 0.f, 0.f};
        for (int t = wv; t < T; t += 2) {
            const float bt = sScal[t];
            const float4 h = sH4[t*D4 + lane];
            acc.x = fmaf(bt, h.x, acc.x); acc.y = fmaf(bt, h.y, acc.y);
            acc.z = fmaf(bt, h.z, acc.z); acc.w = fmaf(bt, h.w, acc.w);
        }
        sHtilP[wv][lane] = acc;
    }
    __syncthreads();   // bar5

    // ---- P7: output. 2t x 25g lanes per pair; U hoisted to regs from GLOBAL;
    //          at-rows loaded STAGGERED (one float4 live at a time) ----
    {
        const int tsel = (lane < 50) ? (lane / 25) : 0;
        const int g    = (lane < 50) ? (lane - tsel*25) : (lane - 50);
        const bool act = (lane < 50);

        const float4 p0 = sHtilP[0][g], p1 = sHtilP[1][g];
        float4 htil;
        htil.x = p0.x+p1.x; htil.y = p0.y+p1.y;
        htil.z = p0.z+p1.z; htil.w = p0.w+p1.w;

        float4 u[Q];                       // 80 VGPRs, static-indexed (global, L2-warm)
        #pragma unroll
        for (int q = 0; q < Q; ++q) u[q] = Ub[q*D4 + g];

        #pragma unroll 1
        for (int pr = wv; pr < 33; pr += 4) {
            const int t   = pr*2 + tsel;
            const bool val = act && (t < T);
            const int tr  = val ? t : 0;

            float4 acc = {0.f, 0.f, 0.f, 0.f};
            #define QSTEP(av, comp, qq) { \
                acc.x = fmaf(av.comp, u[qq].x, acc.x); \
                acc.y = fmaf(av.comp, u[qq].y, acc.y); \
                acc.z = fmaf(av.comp, u[qq].z, acc.z); \
                acc.w = fmaf(av.comp, u[qq].w, acc.w); }
            {
                float4 a = sS4[tr*SP4 + 0];
                QSTEP(a,x,0)  QSTEP(a,y,1)  QSTEP(a,z,2)  QSTEP(a,w,3)
                a = sS4[tr*SP4 + 1];
                QSTEP(a,x,4)  QSTEP(a,y,5)  QSTEP(a,z,6)  QSTEP(a,w,7)
                a = sS4[tr*SP4 + 2];
                QSTEP(a,x,8)  QSTEP(a,y,9)  QSTEP(a,z,10) QSTEP(a,w,11)
                a = sS4[tr*SP4 + 3];
                QSTEP(a,x,12) QSTEP(a,y,13) QSTEP(a,z,14) QSTEP(a,w,15)
                a = sS4[tr*SP4 + 4];
                QSTEP(a,x,16) QSTEP(a,y,17) QSTEP(a,z,18) QSTEP(a,w,19)
            }
            #undef QSTEP

            const float4 hv = sH4[tr*D4 + g];
            if (val) {
                float4 hu, hh;
                hu.x = hv.x*acc.x;  hu.y = hv.y*acc.y;  hu.z = hv.z*acc.z;  hu.w = hv.w*acc.w;
                hh.x = hv.x*htil.x; hh.y = hv.y*htil.y; hh.z = hv.z*htil.z; hh.w = hv.w*htil.w;
                float4* base = (float4*)(Gb + (size_t)t*(4*D));
                base[g]        = hv;
                base[D4 + g]   = acc;
                base[2*D4 + g] = hu;
                base[3*D4 + g] = hh;
            }
        }
    }
}

extern "C" void kernel_launch(void* const* d_in, const int* in_sizes, int n_in,
                              void* d_out, int out_size, void* d_ws, size_t ws_size,
                              hipStream_t stream) {
    const float* H   = (const float*)d_in[0];
    const float* U   = (const float*)d_in[1];
    const float* Ws1 = (const float*)d_in[2];
    const float* Ws2 = (const float*)d_in[3];
    const float* Ws3 = (const float*)d_in[4];
    float* G = (float*)d_out;
    hipLaunchKernelGGL(attn_fused_kernel, dim3(NB), dim3(256), 0, stream,
                       H, U, Ws1, Ws2, Ws3, G);
}